// Round 5
// baseline (255.319 us; speedup 1.0000x reference)
//
#include <hip/hip_runtime.h>

#define Kc 512
#define Dc 64
#define Hc 64
#define Bc 16
#define Tc 16384
#define Nt (Bc * Tc)              // 262144 tokens
#define LN_EPS 1e-5f
// loss = (1 + 0.25) * mean over N*D elements
#define LOSS_SCALE (1.25f / 16777216.0f)   // 1.25 / (Nt*Dc)

#define GATHER_BLOCKS 4096
#define GATHER_THREADS 256
#define GATHER_ITERS 4            // 4096*256*4 = 4,194,304 float4s = Nt*16

// ---------------------------------------------------------------------------
// Kernel 1: per-t-value table precompute. 512 blocks x 256 threads (4 waves).
// Block v: encoder (first wave) -> z[64] -> 4-wave argmin over 512 codewords
// (each thread 2 rows, float4 loads) -> store q row / idx / d2.
// Block 0 also zeroes the gather kernel's done-counter (ws is poisoned 0xAA).
// ---------------------------------------------------------------------------
__global__ __launch_bounds__(256) void precompute_kernel(
    const float* __restrict__ W1, const float* __restrict__ b1,
    const float* __restrict__ ln_g, const float* __restrict__ ln_b,
    const float* __restrict__ W2, const float* __restrict__ b2,
    const float* __restrict__ cb,
    float* __restrict__ q_table, float* __restrict__ idxf_table,
    float* __restrict__ d2_table, int* __restrict__ counter)
{
    const int v   = blockIdx.x;      // t value, 0..511
    const int tid = threadIdx.x;     // 0..255

    if (v == 0 && tid == 0) *counter = 0;   // runs before gather (stream order)

    __shared__ float s_h[Hc];
    __shared__ float s_z[Dc];
    __shared__ float s_bd[4];
    __shared__ int   s_bk[4];
    __shared__ int   s_win;
    __shared__ float s_wd;

    // ---- encoder on the first wave only (lane = H index = D index) ----
    if (tid < 64) {
        const int lane = tid;
        const float norm_t = (float)v * (2.0f / (float)(Kc - 1)) - 1.0f;
        float h = norm_t * W1[lane] + b1[lane];

        float s = h;
        #pragma unroll
        for (int o = 32; o > 0; o >>= 1) s += __shfl_xor(s, o);
        const float mu = s * (1.0f / (float)Hc);
        const float d = h - mu;
        float vs = d * d;
        #pragma unroll
        for (int o = 32; o > 0; o >>= 1) vs += __shfl_xor(vs, o);
        const float var = vs * (1.0f / (float)Hc);
        float hn = d * rsqrtf(var + LN_EPS) * ln_g[lane] + ln_b[lane];
        hn = fmaxf(hn, 0.0f);
        s_h[lane] = hn;
        __builtin_amdgcn_s_waitcnt(0);   // LDS write visible within wave
        // z[lane] = sum_h s_h[h] * W2[h][lane] + b2[lane]
        float z = b2[lane];
        #pragma unroll
        for (int hh = 0; hh < Hc; ++hh) z = fmaf(s_h[hh], W2[hh * Dc + lane], z);
        s_z[lane] = z;
    }
    __syncthreads();

    // ---- argmin: thread handles k = tid and tid+256, float4 row loads ----
    const float4* z4 = (const float4*)s_z;   // same-address LDS reads: broadcast
    float best_d = 3.4e38f;
    int best_k = 0;
    #pragma unroll
    for (int half = 0; half < 2; ++half) {
        const int k = tid + half * 256;      // ascending within thread
        const float4* e4 = (const float4*)(cb + k * Dc);
        float dist = 0.0f;
        #pragma unroll
        for (int q = 0; q < 16; ++q) {       // 16 independent 16B loads in flight
            const float4 e = e4[q];
            const float4 zz = z4[q];
            float d0 = zz.x - e.x, d1 = zz.y - e.y, d2 = zz.z - e.z, d3 = zz.w - e.w;
            dist = fmaf(d0, d0, dist); dist = fmaf(d1, d1, dist);
            dist = fmaf(d2, d2, dist); dist = fmaf(d3, d3, dist);
        }
        if (dist < best_d) { best_d = dist; best_k = k; }  // strict < => first idx
    }
    // wave-level lexicographic (d, k) min
    #pragma unroll
    for (int o = 32; o > 0; o >>= 1) {
        const float od = __shfl_xor(best_d, o);
        const int   ok = __shfl_xor(best_k, o);
        if (od < best_d || (od == best_d && ok < best_k)) { best_d = od; best_k = ok; }
    }
    if ((tid & 63) == 0) { s_bd[tid >> 6] = best_d; s_bk[tid >> 6] = best_k; }
    __syncthreads();
    if (tid == 0) {
        float bd = s_bd[0]; int bk = s_bk[0];
        #pragma unroll
        for (int w = 1; w < 4; ++w) {
            const float od = s_bd[w]; const int ok = s_bk[w];
            if (od < bd || (od == bd && ok < bk)) { bd = od; bk = ok; }
        }
        s_win = bk; s_wd = bd;
    }
    __syncthreads();

    if (tid < 64) q_table[v * Dc + tid] = cb[s_win * Dc + tid];
    if (tid == 0) { idxf_table[v] = (float)s_win; d2_table[v] = s_wd; }
}

// ---------------------------------------------------------------------------
// Kernel 2: gather + loss, single pass. R2 config (4096 blocks, plain float4
// stores through L2 — TLP is the latency hider here, R4 proved cutting blocks
// 4x + NT stores regressed 44->72us). Per-block loss partial -> ws; the LAST
// block (device-scope counter) reduces the 4096 partials -> out_loss.
// ---------------------------------------------------------------------------
__global__ __launch_bounds__(GATHER_THREADS) void gather_kernel(
    const int* __restrict__ t, const float* __restrict__ q_table,
    const float* __restrict__ idxf_table, const float* __restrict__ d2_table,
    float* __restrict__ out_q, float* __restrict__ out_idx,
    float* __restrict__ partials, int* __restrict__ counter,
    float* __restrict__ out_loss)
{
    const int tid = threadIdx.x;
    const int g0  = blockIdx.x * GATHER_THREADS + tid;
    const int stride = GATHER_BLOCKS * GATHER_THREADS;

    float lsum = 0.0f;
    #pragma unroll
    for (int i = 0; i < GATHER_ITERS; ++i) {
        const int g     = g0 + i * stride;      // float4 index
        const int token = g >> 4;
        const int part  = g & 15;
        const int tv = t[token];                // 16 lanes share one dword
        const float4 q = ((const float4*)q_table)[(tv << 4) + part];  // L2-hit
        ((float4*)out_q)[g] = q;                // coalesced 16B/lane store
        if (part == 0) {
            out_idx[token] = idxf_table[tv];
            lsum += d2_table[tv];
        }
    }

    // block reduction -> one partial per block
    #pragma unroll
    for (int o = 32; o > 0; o >>= 1) lsum += __shfl_xor(lsum, o);
    __shared__ float s_partial[4];
    __shared__ int   s_done;
    if ((tid & 63) == 0) s_partial[tid >> 6] = lsum;
    __syncthreads();
    if (tid == 0) {
        const float bs =
            s_partial[0] + s_partial[1] + s_partial[2] + s_partial[3];
        // device-scope release store: visible at the coherence point (cross-XCD)
        __hip_atomic_store(&partials[blockIdx.x], bs, __ATOMIC_RELEASE,
                           __HIP_MEMORY_SCOPE_AGENT);
        const int prev = __hip_atomic_fetch_add(counter, 1, __ATOMIC_ACQ_REL,
                                                __HIP_MEMORY_SCOPE_AGENT);
        s_done = (prev == GATHER_BLOCKS - 1) ? 1 : 0;
    }
    __syncthreads();

    if (s_done) {   // last block: deterministic final reduction
        float s = 0.0f;
        #pragma unroll
        for (int i = 0; i < GATHER_BLOCKS / GATHER_THREADS; ++i)
            s += __hip_atomic_load(&partials[i * GATHER_THREADS + tid],
                                   __ATOMIC_ACQUIRE, __HIP_MEMORY_SCOPE_AGENT);
        #pragma unroll
        for (int o = 32; o > 0; o >>= 1) s += __shfl_xor(s, o);
        __shared__ float s_fin[4];
        if ((tid & 63) == 0) s_fin[tid >> 6] = s;
        __syncthreads();
        if (tid == 0)
            out_loss[0] = (s_fin[0] + s_fin[1] + s_fin[2] + s_fin[3]) * LOSS_SCALE;
    }
}

extern "C" void kernel_launch(void* const* d_in, const int* in_sizes, int n_in,
                              void* d_out, int out_size, void* d_ws, size_t ws_size,
                              hipStream_t stream) {
    const int*   t        = (const int*)d_in[0];     // [B,T,1] int32
    const float* W1       = (const float*)d_in[1];   // [1,H]
    const float* b1       = (const float*)d_in[2];   // [H]
    const float* ln_g     = (const float*)d_in[3];   // [H]
    const float* ln_b     = (const float*)d_in[4];   // [H]
    const float* W2       = (const float*)d_in[5];   // [H,D]
    const float* b2       = (const float*)d_in[6];   // [D]
    const float* codebook = (const float*)d_in[7];   // [K,D]

    float* out      = (float*)d_out;
    float* out_q    = out;                     // Nt*Dc floats
    float* out_idx  = out + (size_t)Nt * Dc;   // Nt floats (idx as float)
    float* out_loss = out_idx + Nt;            // 1 float

    float* ws        = (float*)d_ws;
    float* q_table   = ws;                        // 512*64
    float* idxf_tab  = ws + Kc * Dc;              // 512
    float* d2_tab    = idxf_tab + Kc;             // 512
    float* partials  = d2_tab + Kc;               // 4096
    int*   counter   = (int*)(partials + GATHER_BLOCKS);

    precompute_kernel<<<Kc, 256, 0, stream>>>(
        W1, b1, ln_g, ln_b, W2, b2, codebook,
        q_table, idxf_tab, d2_tab, counter);

    gather_kernel<<<GATHER_BLOCKS, GATHER_THREADS, 0, stream>>>(
        t, q_table, idxf_tab, d2_tab, out_q, out_idx, partials, counter, out_loss);
}

// Round 6
// 110.486 us; speedup vs baseline: 2.3109x; 2.3109x over previous
//
#include <hip/hip_runtime.h>

#define Kc 512
#define Dc 64
#define Hc 64
#define Bc 16
#define Tc 16384
#define Nt (Bc * Tc)              // 262144 tokens
#define LN_EPS 1e-5f
// loss = (1 + 0.25) * mean over N*D elements
#define LOSS_SCALE (1.25f / 16777216.0f)   // 1.25 / (Nt*Dc)

#define GATHER_BLOCKS 4096
#define GATHER_THREADS 256
#define GATHER_ITERS 4            // 4096*256*4 = 4,194,304 float4s = Nt*16

// ---------------------------------------------------------------------------
// Kernel 1: per-t-value table precompute. 512 blocks x 256 threads (4 waves).
// Block v: encoder (first wave) -> z[64] -> 4-wave argmin over 512 codewords
// (each thread 2 rows, float4 loads) -> store q row / idx / d2.
// ---------------------------------------------------------------------------
__global__ __launch_bounds__(256) void precompute_kernel(
    const float* __restrict__ W1, const float* __restrict__ b1,
    const float* __restrict__ ln_g, const float* __restrict__ ln_b,
    const float* __restrict__ W2, const float* __restrict__ b2,
    const float* __restrict__ cb,
    float* __restrict__ q_table, float* __restrict__ idxf_table,
    float* __restrict__ d2_table)
{
    const int v   = blockIdx.x;      // t value, 0..511
    const int tid = threadIdx.x;     // 0..255

    __shared__ float s_h[Hc];
    __shared__ float s_z[Dc];
    __shared__ float s_bd[4];
    __shared__ int   s_bk[4];
    __shared__ int   s_win;
    __shared__ float s_wd;

    // ---- encoder on the first wave only (lane = H index = D index) ----
    if (tid < 64) {
        const int lane = tid;
        const float norm_t = (float)v * (2.0f / (float)(Kc - 1)) - 1.0f;
        float h = norm_t * W1[lane] + b1[lane];

        float s = h;
        #pragma unroll
        for (int o = 32; o > 0; o >>= 1) s += __shfl_xor(s, o);
        const float mu = s * (1.0f / (float)Hc);
        const float d = h - mu;
        float vs = d * d;
        #pragma unroll
        for (int o = 32; o > 0; o >>= 1) vs += __shfl_xor(vs, o);
        const float var = vs * (1.0f / (float)Hc);
        float hn = d * rsqrtf(var + LN_EPS) * ln_g[lane] + ln_b[lane];
        hn = fmaxf(hn, 0.0f);
        s_h[lane] = hn;
        __builtin_amdgcn_s_waitcnt(0);   // LDS write visible within wave
        // z[lane] = sum_h s_h[h] * W2[h][lane] + b2[lane]
        float z = b2[lane];
        #pragma unroll
        for (int hh = 0; hh < Hc; ++hh) z = fmaf(s_h[hh], W2[hh * Dc + lane], z);
        s_z[lane] = z;
    }
    __syncthreads();

    // ---- argmin: thread handles k = tid and tid+256, float4 row loads ----
    const float4* z4 = (const float4*)s_z;   // same-address LDS reads: broadcast
    float best_d = 3.4e38f;
    int best_k = 0;
    #pragma unroll
    for (int half = 0; half < 2; ++half) {
        const int k = tid + half * 256;      // ascending within thread
        const float4* e4 = (const float4*)(cb + k * Dc);
        float dist = 0.0f;
        #pragma unroll
        for (int q = 0; q < 16; ++q) {       // 16 independent 16B loads in flight
            const float4 e = e4[q];
            const float4 zz = z4[q];
            float d0 = zz.x - e.x, d1 = zz.y - e.y, d2 = zz.z - e.z, d3 = zz.w - e.w;
            dist = fmaf(d0, d0, dist); dist = fmaf(d1, d1, dist);
            dist = fmaf(d2, d2, dist); dist = fmaf(d3, d3, dist);
        }
        if (dist < best_d) { best_d = dist; best_k = k; }  // strict < => first idx
    }
    // wave-level lexicographic (d, k) min
    #pragma unroll
    for (int o = 32; o > 0; o >>= 1) {
        const float od = __shfl_xor(best_d, o);
        const int   ok = __shfl_xor(best_k, o);
        if (od < best_d || (od == best_d && ok < best_k)) { best_d = od; best_k = ok; }
    }
    if ((tid & 63) == 0) { s_bd[tid >> 6] = best_d; s_bk[tid >> 6] = best_k; }
    __syncthreads();
    if (tid == 0) {
        float bd = s_bd[0]; int bk = s_bk[0];
        #pragma unroll
        for (int w = 1; w < 4; ++w) {
            const float od = s_bd[w]; const int ok = s_bk[w];
            if (od < bd || (od == bd && ok < bk)) { bd = od; bk = ok; }
        }
        s_win = bk; s_wd = bd;
    }
    __syncthreads();

    if (tid < 64) q_table[v * Dc + tid] = cb[s_win * Dc + tid];
    if (tid == 0) { idxf_table[v] = (float)s_win; d2_table[v] = s_wd; }
}

// ---------------------------------------------------------------------------
// Kernel 2: gather. R2 config (4096 blocks, plain float4 stores through L2,
// plain partial store — R5 proved per-block agent-scope release/acquire is an
// L2-flush storm, 40->180us). NEW vs R2: explicit ILP batching — R2's
// VGPR_Count=12 showed only ONE float4 in flight; batch all 4 iterations'
// t loads, then table loads, then stores to quadruple per-wave MLP.
// ---------------------------------------------------------------------------
__global__ __launch_bounds__(GATHER_THREADS) void gather_kernel(
    const int* __restrict__ t, const float* __restrict__ q_table,
    const float* __restrict__ idxf_table, const float* __restrict__ d2_table,
    float* __restrict__ out_q, float* __restrict__ out_idx,
    float* __restrict__ partials)
{
    const int tid = threadIdx.x;
    const int g0  = blockIdx.x * GATHER_THREADS + tid;
    const int stride = GATHER_BLOCKS * GATHER_THREADS;   // 2^20, %16==0
    const int part  = g0 & 15;                           // same for all iters

    // phase 1: all t loads in flight
    int tvs[GATHER_ITERS];
    #pragma unroll
    for (int i = 0; i < GATHER_ITERS; ++i)
        tvs[i] = t[(g0 + i * stride) >> 4];

    // phase 2: all table reads in flight (L2-resident, 128KB table)
    float4 qs[GATHER_ITERS];
    #pragma unroll
    for (int i = 0; i < GATHER_ITERS; ++i)
        qs[i] = ((const float4*)q_table)[(tvs[i] << 4) + part];

    // phase 3: streaming stores
    #pragma unroll
    for (int i = 0; i < GATHER_ITERS; ++i)
        ((float4*)out_q)[g0 + i * stride] = qs[i];

    // idx + loss contributions (part==0 lanes only; 4 lanes/wave)
    float lsum = 0.0f;
    if (part == 0) {
        #pragma unroll
        for (int i = 0; i < GATHER_ITERS; ++i) {
            const int token = (g0 + i * stride) >> 4;
            out_idx[token] = idxf_table[tvs[i]];
            lsum += d2_table[tvs[i]];
        }
    }

    // block reduction -> one partial per block (plain store; kernel boundary
    // provides cross-XCD visibility for the reduce kernel)
    #pragma unroll
    for (int o = 32; o > 0; o >>= 1) lsum += __shfl_xor(lsum, o);
    __shared__ float s_partial[4];
    if ((tid & 63) == 0) s_partial[tid >> 6] = lsum;
    __syncthreads();
    if (tid == 0)
        partials[blockIdx.x] =
            s_partial[0] + s_partial[1] + s_partial[2] + s_partial[3];
}

// ---------------------------------------------------------------------------
// Kernel 3: reduce 4096 partials -> loss. Single block, deterministic.
// ---------------------------------------------------------------------------
__global__ __launch_bounds__(256) void loss_reduce_kernel(
    const float* __restrict__ partials, float* __restrict__ out_loss)
{
    const int tid = threadIdx.x;
    float s = 0.0f;
    #pragma unroll
    for (int i = 0; i < GATHER_BLOCKS / 256; ++i)
        s += partials[i * 256 + tid];
    #pragma unroll
    for (int o = 32; o > 0; o >>= 1) s += __shfl_xor(s, o);
    __shared__ float s_partial[4];
    if ((tid & 63) == 0) s_partial[tid >> 6] = s;
    __syncthreads();
    if (tid == 0)
        out_loss[0] = (s_partial[0] + s_partial[1] + s_partial[2] + s_partial[3])
                      * LOSS_SCALE;
}

extern "C" void kernel_launch(void* const* d_in, const int* in_sizes, int n_in,
                              void* d_out, int out_size, void* d_ws, size_t ws_size,
                              hipStream_t stream) {
    const int*   t        = (const int*)d_in[0];     // [B,T,1] int32
    const float* W1       = (const float*)d_in[1];   // [1,H]
    const float* b1       = (const float*)d_in[2];   // [H]
    const float* ln_g     = (const float*)d_in[3];   // [H]
    const float* ln_b     = (const float*)d_in[4];   // [H]
    const float* W2       = (const float*)d_in[5];   // [H,D]
    const float* b2       = (const float*)d_in[6];   // [D]
    const float* codebook = (const float*)d_in[7];   // [K,D]

    float* out      = (float*)d_out;
    float* out_q    = out;                     // Nt*Dc floats
    float* out_idx  = out + (size_t)Nt * Dc;   // Nt floats (idx as float)
    float* out_loss = out_idx + Nt;            // 1 float

    float* ws        = (float*)d_ws;
    float* q_table   = ws;                        // 512*64
    float* idxf_tab  = ws + Kc * Dc;              // 512
    float* d2_tab    = idxf_tab + Kc;             // 512
    float* partials  = d2_tab + Kc;               // 4096

    precompute_kernel<<<Kc, 256, 0, stream>>>(
        W1, b1, ln_g, ln_b, W2, b2, codebook,
        q_table, idxf_tab, d2_tab);

    gather_kernel<<<GATHER_BLOCKS, GATHER_THREADS, 0, stream>>>(
        t, q_table, idxf_tab, d2_tab, out_q, out_idx, partials);

    loss_reduce_kernel<<<1, 256, 0, stream>>>(partials, out_loss);
}

// Round 7
// 104.303 us; speedup vs baseline: 2.4479x; 1.0593x over previous
//
#include <hip/hip_runtime.h>

#define Kc 512
#define Dc 64
#define Hc 64
#define Bc 16
#define Tc 16384
#define Nt (Bc * Tc)              // 262144 tokens
#define LN_EPS 1e-5f
// loss = (1 + 0.25) * mean over N*D elements
#define LOSS_SCALE (1.25f / 16777216.0f)   // 1.25 / (Nt*Dc)

#define GATHER_BLOCKS 4096
#define GATHER_THREADS 256
#define GATHER_ITERS 4            // 4096*256*4 = 4,194,304 float4s = Nt*16

// ---------------------------------------------------------------------------
// Kernel 1: per-t-value table precompute. 512 blocks x 256 threads (4 waves).
// Block v: encoder (first wave) -> z[64] -> coalesced 4-wave argmin.
// R7 rewrite: old argmin read one codebook ROW per thread (lane stride 256B
// => 64 cache lines per load instr, ~4.2M L1 transactions, est ~27us).
// Now a wave reads 64 CONSECUTIVE float4s per iter (= 4 whole rows, 4 lines
// per instr); lane l holds dims (l&15)*4..+3 of row rowbase+(l>>4); partial
// dists reduced across the 16-lane group via 4 shfl_xor.
// ---------------------------------------------------------------------------
__global__ __launch_bounds__(256) void precompute_kernel(
    const float* __restrict__ W1, const float* __restrict__ b1,
    const float* __restrict__ ln_g, const float* __restrict__ ln_b,
    const float* __restrict__ W2, const float* __restrict__ b2,
    const float* __restrict__ cb,
    float* __restrict__ q_table, float* __restrict__ idxf_table,
    float* __restrict__ d2_table)
{
    const int v   = blockIdx.x;      // t value, 0..511
    const int tid = threadIdx.x;     // 0..255
    const int lane = tid & 63;
    const int wave = tid >> 6;       // 0..3

    __shared__ float s_h[Hc];
    __shared__ __align__(16) float s_z[Dc];
    __shared__ float s_bd[4];
    __shared__ int   s_bk[4];
    __shared__ int   s_win;
    __shared__ float s_wd;

    // ---- encoder on the first wave only (lane = H index = D index) ----
    if (tid < 64) {
        const float norm_t = (float)v * (2.0f / (float)(Kc - 1)) - 1.0f;
        float h = norm_t * W1[lane] + b1[lane];

        float s = h;
        #pragma unroll
        for (int o = 32; o > 0; o >>= 1) s += __shfl_xor(s, o);
        const float mu = s * (1.0f / (float)Hc);
        const float d = h - mu;
        float vs = d * d;
        #pragma unroll
        for (int o = 32; o > 0; o >>= 1) vs += __shfl_xor(vs, o);
        const float var = vs * (1.0f / (float)Hc);
        float hn = d * rsqrtf(var + LN_EPS) * ln_g[lane] + ln_b[lane];
        hn = fmaxf(hn, 0.0f);
        s_h[lane] = hn;
        __builtin_amdgcn_s_waitcnt(0);   // LDS write visible within wave
        // z[lane] = sum_h s_h[h] * W2[h][lane] + b2[lane]
        float z = b2[lane];
        #pragma unroll
        for (int hh = 0; hh < Hc; ++hh) z = fmaf(s_h[hh], W2[hh * Dc + lane], z);
        s_z[lane] = z;
    }
    __syncthreads();

    // ---- coalesced argmin ----
    // wave w owns rows [w*128, w*128+128). Iter i loads f4 index
    // w*2048 + i*64 + lane: 64 consecutive float4s = rows w*128+i*4+(lane>>4),
    // dims (lane&15)*4..+3. 32 iters cover all 128 rows.
    const float4* cb4 = (const float4*)cb;
    const float4 zz = ((const float4*)s_z)[lane & 15];   // loop-invariant
    const int rowgrp = lane >> 4;                        // 0..3

    float best_d = 3.4e38f;
    int best_k = 0;
    const int base = wave * 2048;
    #pragma unroll 4
    for (int i = 0; i < 32; ++i) {
        const float4 e = cb4[base + i * 64 + lane];
        float d0 = zz.x - e.x, d1 = zz.y - e.y, d2 = zz.z - e.z, d3 = zz.w - e.w;
        float pd = d0 * d0;
        pd = fmaf(d1, d1, pd); pd = fmaf(d2, d2, pd); pd = fmaf(d3, d3, pd);
        // sum the 4-dim partials across the 16-lane group (all lanes get total)
        pd += __shfl_xor(pd, 1);
        pd += __shfl_xor(pd, 2);
        pd += __shfl_xor(pd, 4);
        pd += __shfl_xor(pd, 8);
        const int k = wave * 128 + i * 4 + rowgrp;
        if (pd < best_d) { best_d = pd; best_k = k; }  // k ascends per lane: strict < => first idx
    }
    // wave-level lexicographic (d, k) min
    #pragma unroll
    for (int o = 32; o > 0; o >>= 1) {
        const float od = __shfl_xor(best_d, o);
        const int   ok = __shfl_xor(best_k, o);
        if (od < best_d || (od == best_d && ok < best_k)) { best_d = od; best_k = ok; }
    }
    if (lane == 0) { s_bd[wave] = best_d; s_bk[wave] = best_k; }
    __syncthreads();
    if (tid == 0) {
        float bd = s_bd[0]; int bk = s_bk[0];
        #pragma unroll
        for (int w = 1; w < 4; ++w) {
            const float od = s_bd[w]; const int ok = s_bk[w];
            if (od < bd || (od == bd && ok < bk)) { bd = od; bk = ok; }
        }
        s_win = bk; s_wd = bd;
    }
    __syncthreads();

    if (tid < 64) q_table[v * Dc + tid] = cb[s_win * Dc + tid];
    if (tid == 0) { idxf_table[v] = (float)s_win; d2_table[v] = s_wd; }
}

// ---------------------------------------------------------------------------
// Kernel 2: gather (unchanged from R6). 4096 blocks, plain float4 stores
// through L2, batched ILP, plain partial store (R5: per-block agent-scope
// release/acquire is an L2-flush storm, 40->180us).
// ---------------------------------------------------------------------------
__global__ __launch_bounds__(GATHER_THREADS) void gather_kernel(
    const int* __restrict__ t, const float* __restrict__ q_table,
    const float* __restrict__ idxf_table, const float* __restrict__ d2_table,
    float* __restrict__ out_q, float* __restrict__ out_idx,
    float* __restrict__ partials)
{
    const int tid = threadIdx.x;
    const int g0  = blockIdx.x * GATHER_THREADS + tid;
    const int stride = GATHER_BLOCKS * GATHER_THREADS;   // 2^20, %16==0
    const int part  = g0 & 15;                           // same for all iters

    // phase 1: all t loads in flight
    int tvs[GATHER_ITERS];
    #pragma unroll
    for (int i = 0; i < GATHER_ITERS; ++i)
        tvs[i] = t[(g0 + i * stride) >> 4];

    // phase 2: all table reads in flight (L2/L3-resident, 128KB table)
    float4 qs[GATHER_ITERS];
    #pragma unroll
    for (int i = 0; i < GATHER_ITERS; ++i)
        qs[i] = ((const float4*)q_table)[(tvs[i] << 4) + part];

    // phase 3: streaming stores
    #pragma unroll
    for (int i = 0; i < GATHER_ITERS; ++i)
        ((float4*)out_q)[g0 + i * stride] = qs[i];

    // idx + loss contributions (part==0 lanes only; 4 lanes/wave)
    float lsum = 0.0f;
    if (part == 0) {
        #pragma unroll
        for (int i = 0; i < GATHER_ITERS; ++i) {
            const int token = (g0 + i * stride) >> 4;
            out_idx[token] = idxf_table[tvs[i]];
            lsum += d2_table[tvs[i]];
        }
    }

    // block reduction -> one partial per block (plain store; kernel boundary
    // provides cross-XCD visibility for the reduce kernel)
    #pragma unroll
    for (int o = 32; o > 0; o >>= 1) lsum += __shfl_xor(lsum, o);
    __shared__ float s_partial[4];
    if ((tid & 63) == 0) s_partial[tid >> 6] = lsum;
    __syncthreads();
    if (tid == 0)
        partials[blockIdx.x] =
            s_partial[0] + s_partial[1] + s_partial[2] + s_partial[3];
}

// ---------------------------------------------------------------------------
// Kernel 3: reduce 4096 partials -> loss. Single block, deterministic.
// ---------------------------------------------------------------------------
__global__ __launch_bounds__(256) void loss_reduce_kernel(
    const float* __restrict__ partials, float* __restrict__ out_loss)
{
    const int tid = threadIdx.x;
    float s = 0.0f;
    #pragma unroll
    for (int i = 0; i < GATHER_BLOCKS / 256; ++i)
        s += partials[i * 256 + tid];
    #pragma unroll
    for (int o = 32; o > 0; o >>= 1) s += __shfl_xor(s, o);
    __shared__ float s_partial[4];
    if ((tid & 63) == 0) s_partial[tid >> 6] = s;
    __syncthreads();
    if (tid == 0)
        out_loss[0] = (s_partial[0] + s_partial[1] + s_partial[2] + s_partial[3])
                      * LOSS_SCALE;
}

extern "C" void kernel_launch(void* const* d_in, const int* in_sizes, int n_in,
                              void* d_out, int out_size, void* d_ws, size_t ws_size,
                              hipStream_t stream) {
    const int*   t        = (const int*)d_in[0];     // [B,T,1] int32
    const float* W1       = (const float*)d_in[1];   // [1,H]
    const float* b1       = (const float*)d_in[2];   // [H]
    const float* ln_g     = (const float*)d_in[3];   // [H]
    const float* ln_b     = (const float*)d_in[4];   // [H]
    const float* W2       = (const float*)d_in[5];   // [H,D]
    const float* b2       = (const float*)d_in[6];   // [D]
    const float* codebook = (const float*)d_in[7];   // [K,D]

    float* out      = (float*)d_out;
    float* out_q    = out;                     // Nt*Dc floats
    float* out_idx  = out + (size_t)Nt * Dc;   // Nt floats (idx as float)
    float* out_loss = out_idx + Nt;            // 1 float

    float* ws        = (float*)d_ws;
    float* q_table   = ws;                        // 512*64
    float* idxf_tab  = ws + Kc * Dc;              // 512
    float* d2_tab    = idxf_tab + Kc;             // 512
    float* partials  = d2_tab + Kc;               // 4096

    precompute_kernel<<<Kc, 256, 0, stream>>>(
        W1, b1, ln_g, ln_b, W2, b2, codebook,
        q_table, idxf_tab, d2_tab);

    gather_kernel<<<GATHER_BLOCKS, GATHER_THREADS, 0, stream>>>(
        t, q_table, idxf_tab, d2_tab, out_q, out_idx, partials);

    loss_reduce_kernel<<<1, 256, 0, stream>>>(partials, out_loss);
}